// Round 2
// baseline (522.762 us; speedup 1.0000x reference)
//
#include <hip/hip_runtime.h>
#include <cstdint>

// Problem constants (fixed by reference): B=2, H=32, S=4096, D=128, BLOCK=512
#define NH 32
#define SEQ 4096
#define DDIM 128
#define BSZ 512
#define SKC 64            // token chunk per staging pass
#define NCH 8             // 512 / 64
#define ST_STRIDE 68      // dwords per sT row (64 data + 4 pad -> 16B-aligned b128)

// Phase-1 double buffers: 128 rows x 32 dwords each, XOR-swizzled 16B blocks
#define OFF_K0 0
#define OFF_V0 4096
#define OFF_K1 8192
#define OFF_V1 12288      // phase-1 end = 16384 dw
// Phase-2 S^T aliases the phase-1 region (separated by barrier)
#define OFF_ST 0          // 128 x 68 = 8704 dw
#define OFF_Z  16384      // 128 f32 (no alias)
#define OFF_SC 16512      // 128 f32 phi_scale copy
#define OFF_SB 16640      // 128 f32 phi_bias copy
#define LDS_DW 16768      // 67072 B -> 2 blocks/CU (132 KB of 160 KB)

typedef _Float16 f16x8 __attribute__((ext_vector_type(8)));
typedef float f32x4 __attribute__((ext_vector_type(4)));

union FragU { uint32_t u[4]; f16x8 v; };

__device__ __forceinline__ float phi_fn(float x, float s, float b) {
    float y = fmaf(x, s, b);
    return y > 0.0f ? (y + 1.0f) : __expf(y);   // elu(y)+1
}

__device__ __forceinline__ uint32_t pack_f16(float a, float b) {
    union { _Float16 h[2]; uint32_t u; } p;
    p.h[0] = (_Float16)a;
    p.h[1] = (_Float16)b;
    return p.u;
}

__global__ __launch_bounds__(512, 4) void linattn_kernel(
    const float* __restrict__ qg, const float* __restrict__ kg,
    const float* __restrict__ vg, const float* __restrict__ psg,
    const float* __restrict__ pbg, float* __restrict__ outg)
{
    __shared__ uint32_t lds[LDS_DW];
    float*    ldsf = (float*)lds;
    _Float16* ldsh = (_Float16*)lds;

    const int tid  = threadIdx.x;
    const int lane = tid & 63;
    const int wv   = tid >> 6;          // 0..7
    const int l15  = lane & 15;
    const int qd   = lane >> 4;         // 0..3

    const int gid = blockIdx.x;          // 512 = B*H*nb
    const int nb  = gid & 7;
    const int hh  = (gid >> 3) & 31;
    const int bb  = gid >> 8;

    const size_t base = ((size_t)(bb * NH + hh) * SEQ + (size_t)nb * BSZ) * DDIM;

    // Setup: copy phi params to LDS (for phase-2 per-lane access) + zero Z
    if (tid < 32) {
        *(f32x4*)(ldsf + OFF_SC + tid * 4) = *(const f32x4*)(psg + hh * DDIM + tid * 4);
    } else if (tid < 64) {
        *(f32x4*)(ldsf + OFF_SB + (tid - 32) * 4) = *(const f32x4*)(pbg + hh * DDIM + (tid - 32) * 4);
    }
    if (tid < 128) ldsf[OFF_Z + tid] = 0.0f;

    // ---------------- Phase 1: S^T = V^T * phi_K, Z = colsum(phi_K) ----------------
    // Staging map: thread owns dim-pair (2dp, 2dp+1) for dp=lane; wave wv stages
    // tokens wv*8 .. wv*8+7 of each 64-token chunk (perfectly coalesced float2).
    const int dp = lane;
    const float2 sc2 = *(const float2*)(psg + hh * DDIM + 2 * dp);
    const float2 bi2 = *(const float2*)(pbg + hh * DDIM + 2 * dp);

    float z0 = 0.0f, z1 = 0.0f;

    // S^T accumulators: wave wv owns m-rows [wv*16, wv*16+16): 1 m-tile x 8 d-tiles
    f32x4 acc[8];
    #pragma unroll
    for (int c = 0; c < 8; ++c) acc[c] = (f32x4){0.f, 0.f, 0.f, 0.f};

    float2 kr[8], vr[8];               // prefetch registers (one chunk)
    const float* kbase = kg + base + 2 * dp;
    const float* vbase = vg + base + 2 * dp;

    auto loadkv = [&](int ch) {
        const size_t off = (size_t)(ch * SKC + wv * 8) * DDIM;
        #pragma unroll
        for (int j = 0; j < 8; ++j) {
            kr[j] = *(const float2*)(kbase + off + (size_t)j * DDIM);
            vr[j] = *(const float2*)(vbase + off + (size_t)j * DDIM);
        }
    };

    // LDS layout: addr(row d, tokpair tp) = d*32 + (((tp>>2) ^ ((d>>1)&7))<<2) + (tp&3)
    // -> uint4 writes and b128 reads are both exactly-minimal bank depth.
    auto stagekv = [&](int buf) {
        uint32_t* bk = lds + (buf ? OFF_K1 : OFF_K0);
        uint32_t* bv = lds + (buf ? OFF_V1 : OFF_V0);
        const int blk = ((wv ^ (dp & 7)) << 2);
        uint32_t* k0 = bk + (2 * dp) * 32 + blk;   // row 2dp
        uint32_t* k1 = k0 + 32;                    // row 2dp+1 (same swizzle: (d>>1) equal)
        uint32_t* v0 = bv + (2 * dp) * 32 + blk;
        uint32_t* v1 = v0 + 32;
        float px[8], py[8];
        #pragma unroll
        for (int j = 0; j < 8; ++j) {
            px[j] = phi_fn(kr[j].x, sc2.x, bi2.x);
            py[j] = phi_fn(kr[j].y, sc2.y, bi2.y);
            z0 += px[j];
            z1 += py[j];
        }
        uint4 a;
        a.x = pack_f16(px[0], px[1]); a.y = pack_f16(px[2], px[3]);
        a.z = pack_f16(px[4], px[5]); a.w = pack_f16(px[6], px[7]);
        *(uint4*)k0 = a;
        a.x = pack_f16(py[0], py[1]); a.y = pack_f16(py[2], py[3]);
        a.z = pack_f16(py[4], py[5]); a.w = pack_f16(py[6], py[7]);
        *(uint4*)k1 = a;
        a.x = pack_f16(vr[0].x, vr[1].x); a.y = pack_f16(vr[2].x, vr[3].x);
        a.z = pack_f16(vr[4].x, vr[5].x); a.w = pack_f16(vr[6].x, vr[7].x);
        *(uint4*)v0 = a;
        a.x = pack_f16(vr[0].y, vr[1].y); a.y = pack_f16(vr[2].y, vr[3].y);
        a.z = pack_f16(vr[4].y, vr[5].y); a.w = pack_f16(vr[6].y, vr[7].y);
        *(uint4*)v1 = a;
    };

    auto mfma1 = [&](int buf) {
        const uint32_t* bk = lds + (buf ? OFF_K1 : OFF_K0);
        const uint32_t* bv = lds + (buf ? OFF_V1 : OFF_V0);
        const int swz = (l15 >> 1) & 7;
        #pragma unroll
        for (int ks = 0; ks < 2; ++ks) {           // K=32 tokens per MFMA step
            const int coff = (((ks * 4 + qd) ^ swz) << 2);
            FragU af;
            const uint4 ta = *(const uint4*)(bv + (wv * 16 + l15) * 32 + coff);
            af.u[0] = ta.x; af.u[1] = ta.y; af.u[2] = ta.z; af.u[3] = ta.w;
            #pragma unroll
            for (int td = 0; td < 8; ++td) {
                const uint4 tb = *(const uint4*)(bk + (td * 16 + l15) * 32 + coff);
                FragU bf;
                bf.u[0] = tb.x; bf.u[1] = tb.y; bf.u[2] = tb.z; bf.u[3] = tb.w;
                acc[td] = __builtin_amdgcn_mfma_f32_16x16x32_f16(af.v, bf.v, acc[td], 0, 0, 0);
            }
        }
    };

    loadkv(0);
    stagekv(0);          // chunk 0 -> buf0 (waits its loads)
    loadkv(1);
    __syncthreads();
    for (int ch = 0; ch < NCH; ++ch) {
        if (ch + 1 < NCH) stagekv((ch + 1) & 1);   // stage regs (chunk ch+1) -> other buf
        if (ch + 2 < NCH) loadkv(ch + 2);          // prefetch ch+2 while MFMA(ch) runs
        mfma1(ch & 1);
        __syncthreads();
    }

    atomicAdd(&ldsf[OFF_Z + 2 * dp],     z0);
    atomicAdd(&ldsf[OFF_Z + 2 * dp + 1], z1);

    // Spill S^T (fp16) to LDS: C/D layout row = wv*16 + qd*4 + r, col = td*16 + l15
    #pragma unroll
    for (int td = 0; td < 8; ++td)
        #pragma unroll
        for (int r = 0; r < 4; ++r)
            ldsh[(wv * 16 + qd * 4 + r) * (ST_STRIDE * 2) + td * 16 + l15] = (_Float16)acc[td][r];

    __syncthreads();     // sT + Z + phi-param copies all visible

    // ---------------- Phase 2: num = phi_Q * S, den = phi_Q . Z ----------------
    // Barrier-free: each wave independently streams its 64 q-rows. A-fragments of
    // phi_Q are built in registers directly from global loads (lane = row l15,
    // k-dims = ks*32 + qd*8 + j), den reduced via shfl_xor across the 4 qd groups.
    const float* qb = qg + base;
    float* ob = outg + base;

    #pragma unroll 1
    for (int mt = 0; mt < 4; ++mt) {
        const int rowA = wv * 64 + mt * 16 + l15;
        const float* qrow = qb + (size_t)rowA * DDIM;

        FragU af[4];
        float den = 0.0f;
        #pragma unroll
        for (int ks = 0; ks < 4; ++ks) {
            const int dofs = ks * 32 + qd * 8;
            const f32x4 qa  = *(const f32x4*)(qrow + dofs);
            const f32x4 qc  = *(const f32x4*)(qrow + dofs + 4);
            const f32x4 sa  = *(const f32x4*)(ldsf + OFF_SC + dofs);
            const f32x4 sb  = *(const f32x4*)(ldsf + OFF_SC + dofs + 4);
            const f32x4 ba  = *(const f32x4*)(ldsf + OFF_SB + dofs);
            const f32x4 bbv = *(const f32x4*)(ldsf + OFF_SB + dofs + 4);
            const f32x4 za  = *(const f32x4*)(ldsf + OFF_Z + dofs);
            const f32x4 zb  = *(const f32x4*)(ldsf + OFF_Z + dofs + 4);
            float p[8];
            #pragma unroll
            for (int j = 0; j < 4; ++j) {
                p[j]     = phi_fn(qa[j], sa[j], ba[j]);
                p[4 + j] = phi_fn(qc[j], sb[j], bbv[j]);
                den += p[j] * za[j] + p[4 + j] * zb[j];
            }
            af[ks].u[0] = pack_f16(p[0], p[1]);
            af[ks].u[1] = pack_f16(p[2], p[3]);
            af[ks].u[2] = pack_f16(p[4], p[5]);
            af[ks].u[3] = pack_f16(p[6], p[7]);
        }
        den += __shfl_xor(den, 16);
        den += __shfl_xor(den, 32);    // all lanes: den for row (.. + l15)

        f32x4 acc2[8];
        #pragma unroll
        for (int c = 0; c < 8; ++c) acc2[c] = (f32x4){0.f, 0.f, 0.f, 0.f};

        #pragma unroll
        for (int ks = 0; ks < 4; ++ks) {
            #pragma unroll
            for (int tn = 0; tn < 8; ++tn) {
                const uint4 t1 = *(const uint4*)(lds + OFF_ST + (tn * 16 + l15) * ST_STRIDE + ks * 16 + qd * 4);
                FragU bf;
                bf.u[0] = t1.x; bf.u[1] = t1.y; bf.u[2] = t1.z; bf.u[3] = t1.w;
                acc2[tn] = __builtin_amdgcn_mfma_f32_16x16x32_f16(af[ks].v, bf.v, acc2[tn], 0, 0, 0);
            }
        }

        // Epilogue: out = num / (den + eps), non-temporal stores
        #pragma unroll
        for (int r = 0; r < 4; ++r) {
            const float dv = __shfl(den, qd * 4 + r);   // lane qd*4+r holds that row's den
            const float rden = 1.0f / (dv + 1e-6f);
            float* op = ob + (size_t)(wv * 64 + mt * 16 + qd * 4 + r) * DDIM;
            #pragma unroll
            for (int tn = 0; tn < 8; ++tn)
                __builtin_nontemporal_store(acc2[tn][r] * rden, op + tn * 16 + l15);
        }
    }
}

extern "C" void kernel_launch(void* const* d_in, const int* in_sizes, int n_in,
                              void* d_out, int out_size, void* d_ws, size_t ws_size,
                              hipStream_t stream) {
    const float* q  = (const float*)d_in[0];
    const float* k  = (const float*)d_in[1];
    const float* v  = (const float*)d_in[2];
    const float* ps = (const float*)d_in[3];
    const float* pb = (const float*)d_in[4];
    float* out = (float*)d_out;
    // grid = B*H*nb = 2*32*8 = 512 workgroups, 512 threads (8 waves) each
    linattn_kernel<<<dim3(512), dim3(512), 0, stream>>>(q, k, v, ps, pb, out);
}

// Round 3
// 418.772 us; speedup vs baseline: 1.2483x; 1.2483x over previous
//
#include <hip/hip_runtime.h>
#include <cstdint>

// Problem constants (fixed by reference): B=2, H=32, S=4096, D=128, BLOCK=512
#define NH 32
#define SEQ 4096
#define DDIM 128
#define BSZ 512
#define SKC 64            // token chunk per staging pass
#define NCH 8             // 512 / 64
#define ST_STRIDE 68      // dwords per sT row (64 data + 4 pad -> 16B-aligned b128)

// Phase-1 double buffers: 128 rows x 32 dwords each, XOR-swizzled 16B blocks
#define OFF_K0 0
#define OFF_V0 4096
#define OFF_K1 8192
#define OFF_V1 12288      // phase-1 end = 16384 dw
// Phase-2 S^T aliases the phase-1 region (separated by barrier)
#define OFF_ST 0          // 128 x 68 = 8704 dw
#define OFF_Z  16384      // 128 f32 (no alias)
#define OFF_SC 16512      // 128 f32 phi_scale copy
#define OFF_SB 16640      // 128 f32 phi_bias copy
#define LDS_DW 16768      // 67072 B -> 2 blocks/CU (132 KB of 160 KB)

typedef _Float16 f16x8 __attribute__((ext_vector_type(8)));
typedef float f32x4 __attribute__((ext_vector_type(4)));

union FragU { uint32_t u[4]; f16x8 v; };

__device__ __forceinline__ float phi_fn(float x, float s, float b) {
    float y = fmaf(x, s, b);
    return y > 0.0f ? (y + 1.0f) : __expf(y);   // elu(y)+1
}

__device__ __forceinline__ uint32_t pack_f16(float a, float b) {
    union { _Float16 h[2]; uint32_t u; } p;
    p.h[0] = (_Float16)a;
    p.h[1] = (_Float16)b;
    return p.u;
}

// NOTE: 2nd launch_bounds arg behaves CUDA-style (min BLOCKS/CU) on this
// toolchain: round-1's (512,4) produced VGPR_Count=64 (=512/8, i.e. 4 blocks
// x 8 waves budget) and spilled ~306 MB to scratch. (512,2) -> 128-VGPR cap,
// matching the LDS limit of 2 blocks/CU. Do not raise it.
__global__ __launch_bounds__(512, 2) void linattn_kernel(
    const float* __restrict__ qg, const float* __restrict__ kg,
    const float* __restrict__ vg, const float* __restrict__ psg,
    const float* __restrict__ pbg, float* __restrict__ outg)
{
    __shared__ uint32_t lds[LDS_DW];
    float*    ldsf = (float*)lds;
    _Float16* ldsh = (_Float16*)lds;

    const int tid  = threadIdx.x;
    const int lane = tid & 63;
    const int wv   = tid >> 6;          // 0..7
    const int l15  = lane & 15;
    const int qd   = lane >> 4;         // 0..3

    const int gid = blockIdx.x;          // 512 = B*H*nb
    const int nb  = gid & 7;
    const int hh  = (gid >> 3) & 31;
    const int bb  = gid >> 8;

    const size_t base = ((size_t)(bb * NH + hh) * SEQ + (size_t)nb * BSZ) * DDIM;

    // Setup: copy phi params to LDS (for phase-2 per-lane access) + zero Z
    if (tid < 32) {
        *(f32x4*)(ldsf + OFF_SC + tid * 4) = *(const f32x4*)(psg + hh * DDIM + tid * 4);
    } else if (tid < 64) {
        *(f32x4*)(ldsf + OFF_SB + (tid - 32) * 4) = *(const f32x4*)(pbg + hh * DDIM + (tid - 32) * 4);
    }
    if (tid < 128) ldsf[OFF_Z + tid] = 0.0f;

    // ---------------- Phase 1: S^T = V^T * phi_K, Z = colsum(phi_K) ----------------
    // Staging map: thread owns dim-pair (2dp, 2dp+1) for dp=lane; wave wv stages
    // tokens wv*8 .. wv*8+7 of each 64-token chunk (perfectly coalesced float2).
    const int dp = lane;
    const float2 sc2 = *(const float2*)(psg + hh * DDIM + 2 * dp);
    const float2 bi2 = *(const float2*)(pbg + hh * DDIM + 2 * dp);

    float z0 = 0.0f, z1 = 0.0f;

    // S^T accumulators: wave wv owns m-rows [wv*16, wv*16+16): 1 m-tile x 8 d-tiles
    f32x4 acc[8];
    #pragma unroll
    for (int c = 0; c < 8; ++c) acc[c] = (f32x4){0.f, 0.f, 0.f, 0.f};

    float2 kr[8], vr[8];               // prefetch registers (one chunk)
    const float* kbase = kg + base + 2 * dp;
    const float* vbase = vg + base + 2 * dp;

    auto loadkv = [&](int ch) {
        const size_t off = (size_t)(ch * SKC + wv * 8) * DDIM;
        #pragma unroll
        for (int j = 0; j < 8; ++j) {
            kr[j] = *(const float2*)(kbase + off + (size_t)j * DDIM);
            vr[j] = *(const float2*)(vbase + off + (size_t)j * DDIM);
        }
    };

    // LDS layout: addr(row d, tokpair tp) = d*32 + (((tp>>2) ^ ((d>>1)&7))<<2) + (tp&3)
    // -> uint4 writes and b128 reads are both exactly-minimal bank depth.
    auto stagekv = [&](int buf) {
        uint32_t* bk = lds + (buf ? OFF_K1 : OFF_K0);
        uint32_t* bv = lds + (buf ? OFF_V1 : OFF_V0);
        const int blk = ((wv ^ (dp & 7)) << 2);
        uint32_t* k0 = bk + (2 * dp) * 32 + blk;   // row 2dp
        uint32_t* k1 = k0 + 32;                    // row 2dp+1 (same swizzle: (d>>1) equal)
        uint32_t* v0 = bv + (2 * dp) * 32 + blk;
        uint32_t* v1 = v0 + 32;
        float px[8], py[8];
        #pragma unroll
        for (int j = 0; j < 8; ++j) {
            px[j] = phi_fn(kr[j].x, sc2.x, bi2.x);
            py[j] = phi_fn(kr[j].y, sc2.y, bi2.y);
            z0 += px[j];
            z1 += py[j];
        }
        uint4 a;
        a.x = pack_f16(px[0], px[1]); a.y = pack_f16(px[2], px[3]);
        a.z = pack_f16(px[4], px[5]); a.w = pack_f16(px[6], px[7]);
        *(uint4*)k0 = a;
        a.x = pack_f16(py[0], py[1]); a.y = pack_f16(py[2], py[3]);
        a.z = pack_f16(py[4], py[5]); a.w = pack_f16(py[6], py[7]);
        *(uint4*)k1 = a;
        a.x = pack_f16(vr[0].x, vr[1].x); a.y = pack_f16(vr[2].x, vr[3].x);
        a.z = pack_f16(vr[4].x, vr[5].x); a.w = pack_f16(vr[6].x, vr[7].x);
        *(uint4*)v0 = a;
        a.x = pack_f16(vr[0].y, vr[1].y); a.y = pack_f16(vr[2].y, vr[3].y);
        a.z = pack_f16(vr[4].y, vr[5].y); a.w = pack_f16(vr[6].y, vr[7].y);
        *(uint4*)v1 = a;
    };

    auto mfma1 = [&](int buf) {
        const uint32_t* bk = lds + (buf ? OFF_K1 : OFF_K0);
        const uint32_t* bv = lds + (buf ? OFF_V1 : OFF_V0);
        const int swz = (l15 >> 1) & 7;
        #pragma unroll
        for (int ks = 0; ks < 2; ++ks) {           // K=32 tokens per MFMA step
            const int coff = (((ks * 4 + qd) ^ swz) << 2);
            FragU af;
            const uint4 ta = *(const uint4*)(bv + (wv * 16 + l15) * 32 + coff);
            af.u[0] = ta.x; af.u[1] = ta.y; af.u[2] = ta.z; af.u[3] = ta.w;
            #pragma unroll
            for (int td = 0; td < 8; ++td) {
                const uint4 tb = *(const uint4*)(bk + (td * 16 + l15) * 32 + coff);
                FragU bf;
                bf.u[0] = tb.x; bf.u[1] = tb.y; bf.u[2] = tb.z; bf.u[3] = tb.w;
                acc[td] = __builtin_amdgcn_mfma_f32_16x16x32_f16(af.v, bf.v, acc[td], 0, 0, 0);
            }
        }
    };

    loadkv(0);
    stagekv(0);          // chunk 0 -> buf0 (waits its loads)
    loadkv(1);
    __syncthreads();
    for (int ch = 0; ch < NCH; ++ch) {
        if (ch + 1 < NCH) stagekv((ch + 1) & 1);   // stage regs (chunk ch+1) -> other buf
        if (ch + 2 < NCH) loadkv(ch + 2);          // prefetch ch+2 while MFMA(ch) runs
        mfma1(ch & 1);
        __syncthreads();
    }

    atomicAdd(&ldsf[OFF_Z + 2 * dp],     z0);
    atomicAdd(&ldsf[OFF_Z + 2 * dp + 1], z1);

    // Spill S^T (fp16) to LDS: C/D layout row = wv*16 + qd*4 + r, col = td*16 + l15
    #pragma unroll
    for (int td = 0; td < 8; ++td)
        #pragma unroll
        for (int r = 0; r < 4; ++r)
            ldsh[(wv * 16 + qd * 4 + r) * (ST_STRIDE * 2) + td * 16 + l15] = (_Float16)acc[td][r];

    __syncthreads();     // sT + Z + phi-param copies all visible

    // ---------------- Phase 2: num = phi_Q * S, den = phi_Q . Z ----------------
    // Barrier-free: each wave independently streams its 64 q-rows. A-fragments of
    // phi_Q are built in registers directly from global loads (lane = row l15,
    // k-dims = ks*32 + qd*8 + j), den reduced via shfl_xor across the 4 qd groups.
    const float* qb = qg + base;
    float* ob = outg + base;

    #pragma unroll 1
    for (int mt = 0; mt < 4; ++mt) {
        const int rowA = wv * 64 + mt * 16 + l15;
        const float* qrow = qb + (size_t)rowA * DDIM;

        FragU af[4];
        float den = 0.0f;
        #pragma unroll
        for (int ks = 0; ks < 4; ++ks) {
            const int dofs = ks * 32 + qd * 8;
            const f32x4 qa  = *(const f32x4*)(qrow + dofs);
            const f32x4 qc  = *(const f32x4*)(qrow + dofs + 4);
            const f32x4 sa  = *(const f32x4*)(ldsf + OFF_SC + dofs);
            const f32x4 sb  = *(const f32x4*)(ldsf + OFF_SC + dofs + 4);
            const f32x4 ba  = *(const f32x4*)(ldsf + OFF_SB + dofs);
            const f32x4 bbv = *(const f32x4*)(ldsf + OFF_SB + dofs + 4);
            const f32x4 za  = *(const f32x4*)(ldsf + OFF_Z + dofs);
            const f32x4 zb  = *(const f32x4*)(ldsf + OFF_Z + dofs + 4);
            float p[8];
            #pragma unroll
            for (int j = 0; j < 4; ++j) {
                p[j]     = phi_fn(qa[j], sa[j], ba[j]);
                p[4 + j] = phi_fn(qc[j], sb[j], bbv[j]);
                den += p[j] * za[j] + p[4 + j] * zb[j];
            }
            af[ks].u[0] = pack_f16(p[0], p[1]);
            af[ks].u[1] = pack_f16(p[2], p[3]);
            af[ks].u[2] = pack_f16(p[4], p[5]);
            af[ks].u[3] = pack_f16(p[6], p[7]);
        }
        den += __shfl_xor(den, 16);
        den += __shfl_xor(den, 32);    // all lanes: den for row (.. + l15)

        f32x4 acc2[8];
        #pragma unroll
        for (int c = 0; c < 8; ++c) acc2[c] = (f32x4){0.f, 0.f, 0.f, 0.f};

        #pragma unroll
        for (int ks = 0; ks < 4; ++ks) {
            #pragma unroll
            for (int tn = 0; tn < 8; ++tn) {
                const uint4 t1 = *(const uint4*)(lds + OFF_ST + (tn * 16 + l15) * ST_STRIDE + ks * 16 + qd * 4);
                FragU bf;
                bf.u[0] = t1.x; bf.u[1] = t1.y; bf.u[2] = t1.z; bf.u[3] = t1.w;
                acc2[tn] = __builtin_amdgcn_mfma_f32_16x16x32_f16(af[ks].v, bf.v, acc2[tn], 0, 0, 0);
            }
        }

        // Epilogue: out = num / (den + eps), non-temporal stores
        #pragma unroll
        for (int r = 0; r < 4; ++r) {
            const float dv = __shfl(den, qd * 4 + r);   // lane qd*4+r holds that row's den
            const float rden = 1.0f / (dv + 1e-6f);
            float* op = ob + (size_t)(wv * 64 + mt * 16 + qd * 4 + r) * DDIM;
            #pragma unroll
            for (int tn = 0; tn < 8; ++tn)
                __builtin_nontemporal_store(acc2[tn][r] * rden, op + tn * 16 + l15);
        }
    }
}

extern "C" void kernel_launch(void* const* d_in, const int* in_sizes, int n_in,
                              void* d_out, int out_size, void* d_ws, size_t ws_size,
                              hipStream_t stream) {
    const float* q  = (const float*)d_in[0];
    const float* k  = (const float*)d_in[1];
    const float* v  = (const float*)d_in[2];
    const float* ps = (const float*)d_in[3];
    const float* pb = (const float*)d_in[4];
    float* out = (float*)d_out;
    // grid = B*H*nb = 2*32*8 = 512 workgroups, 512 threads (8 waves) each
    linattn_kernel<<<dim3(512), dim3(512), 0, stream>>>(q, k, v, ps, pb, out);
}

// Round 4
// 398.806 us; speedup vs baseline: 1.3108x; 1.0501x over previous
//
#include <hip/hip_runtime.h>
#include <cstdint>

// Problem constants (fixed by reference): B=2, H=32, S=4096, D=128, BLOCK=512
#define NH 32
#define SEQ 4096
#define DDIM 128
#define BSZ 512
#define SKC 64            // token chunk per staging pass
#define NCH 8             // 512 / 64
#define ST_STRIDE 68      // dwords per sT row (64 data + 4 pad -> 16B-aligned b128)

// Phase-1 double buffers: 128 rows x 32 dwords each, XOR-swizzled 16B blocks
#define OFF_K0 0
#define OFF_V0 4096
#define OFF_K1 8192
#define OFF_V1 12288      // phase-1 end = 16384 dw
// Phase-2 S^T aliases the phase-1 region (separated by barrier)
#define OFF_ST 0          // 128 x 68 = 8704 dw
#define OFF_Z  16384      // 128 f32 (no alias)
#define OFF_SC 16512      // 128 f32 phi_scale copy
#define OFF_SB 16640      // 128 f32 phi_bias copy
#define LDS_DW 16768      // 67072 B -> 2 blocks/CU (132 KB of 160 KB)

typedef _Float16 f16x8 __attribute__((ext_vector_type(8)));
typedef float f32x4 __attribute__((ext_vector_type(4)));

union FragU { uint32_t u[4]; f16x8 v; };

__device__ __forceinline__ float phi_fn(float x, float s, float b) {
    float y = fmaf(x, s, b);
    return y > 0.0f ? (y + 1.0f) : __expf(y);   // elu(y)+1
}

__device__ __forceinline__ uint32_t pack_f16(float a, float b) {
    union { _Float16 h[2]; uint32_t u; } p;
    p.h[0] = (_Float16)a;
    p.h[1] = (_Float16)b;
    return p.u;
}

// NOTE: 2nd launch_bounds arg behaves CUDA-style (min BLOCKS/CU) on this
// toolchain: (512,4) produced VGPR cap 64 (spilled ~306 MB); (512,2) -> 128
// cap, matching the LDS limit of 2 blocks/CU. Keep at 2.
// Round-3 lesson: at exactly 128 arch VGPRs the accumulator arrays overflow
// to AGPRs (unified file) -> 192 total/thread -> 1 block/CU (Occupancy 21%).
// Phase-2 is therefore restructured (tn-outer, single f32x4 accumulator) so
// total pressure stays below 128.
__global__ __launch_bounds__(512, 2) void linattn_kernel(
    const float* __restrict__ qg, const float* __restrict__ kg,
    const float* __restrict__ vg, const float* __restrict__ psg,
    const float* __restrict__ pbg, float* __restrict__ outg)
{
    __shared__ uint32_t lds[LDS_DW];
    float*    ldsf = (float*)lds;
    _Float16* ldsh = (_Float16*)lds;

    const int tid  = threadIdx.x;
    const int lane = tid & 63;
    const int wv   = tid >> 6;          // 0..7
    const int l15  = lane & 15;
    const int qd   = lane >> 4;         // 0..3

    const int gid = blockIdx.x;          // 512 = B*H*nb
    const int nb  = gid & 7;
    const int hh  = (gid >> 3) & 31;
    const int bb  = gid >> 8;

    const size_t base = ((size_t)(bb * NH + hh) * SEQ + (size_t)nb * BSZ) * DDIM;

    // Setup: copy phi params to LDS (for phase-2 per-lane access) + zero Z
    if (tid < 32) {
        *(f32x4*)(ldsf + OFF_SC + tid * 4) = *(const f32x4*)(psg + hh * DDIM + tid * 4);
    } else if (tid < 64) {
        *(f32x4*)(ldsf + OFF_SB + (tid - 32) * 4) = *(const f32x4*)(pbg + hh * DDIM + (tid - 32) * 4);
    }
    if (tid < 128) ldsf[OFF_Z + tid] = 0.0f;

    // ---------------- Phase 1: S^T = V^T * phi_K, Z = colsum(phi_K) ----------------
    // Staging map: thread owns dim-pair (2dp, 2dp+1) for dp=lane; wave wv stages
    // tokens wv*8 .. wv*8+7 of each 64-token chunk (perfectly coalesced float2).
    const int dp = lane;
    const float2 sc2 = *(const float2*)(psg + hh * DDIM + 2 * dp);
    const float2 bi2 = *(const float2*)(pbg + hh * DDIM + 2 * dp);

    float z0 = 0.0f, z1 = 0.0f;

    // S^T accumulators: wave wv owns m-rows [wv*16, wv*16+16): 1 m-tile x 8 d-tiles
    f32x4 acc[8];
    #pragma unroll
    for (int c = 0; c < 8; ++c) acc[c] = (f32x4){0.f, 0.f, 0.f, 0.f};

    float2 kr[8], vr[8];               // prefetch registers (one chunk)
    const float* kbase = kg + base + 2 * dp;
    const float* vbase = vg + base + 2 * dp;

    auto loadkv = [&](int ch) {
        const size_t off = (size_t)(ch * SKC + wv * 8) * DDIM;
        #pragma unroll
        for (int j = 0; j < 8; ++j) {
            kr[j] = *(const float2*)(kbase + off + (size_t)j * DDIM);
            vr[j] = *(const float2*)(vbase + off + (size_t)j * DDIM);
        }
    };

    // LDS layout: addr(row d, tokpair tp) = d*32 + (((tp>>2) ^ ((d>>1)&7))<<2) + (tp&3)
    // -> uint4 writes and b128 reads are both exactly-minimal bank depth.
    auto stagekv = [&](int buf) {
        uint32_t* bk = lds + (buf ? OFF_K1 : OFF_K0);
        uint32_t* bv = lds + (buf ? OFF_V1 : OFF_V0);
        const int blk = ((wv ^ (dp & 7)) << 2);
        uint32_t* k0 = bk + (2 * dp) * 32 + blk;   // row 2dp
        uint32_t* k1 = k0 + 32;                    // row 2dp+1 (same swizzle: (d>>1) equal)
        uint32_t* v0 = bv + (2 * dp) * 32 + blk;
        uint32_t* v1 = v0 + 32;
        float px[8], py[8];
        #pragma unroll
        for (int j = 0; j < 8; ++j) {
            px[j] = phi_fn(kr[j].x, sc2.x, bi2.x);
            py[j] = phi_fn(kr[j].y, sc2.y, bi2.y);
            z0 += px[j];
            z1 += py[j];
        }
        uint4 a;
        a.x = pack_f16(px[0], px[1]); a.y = pack_f16(px[2], px[3]);
        a.z = pack_f16(px[4], px[5]); a.w = pack_f16(px[6], px[7]);
        *(uint4*)k0 = a;
        a.x = pack_f16(py[0], py[1]); a.y = pack_f16(py[2], py[3]);
        a.z = pack_f16(py[4], py[5]); a.w = pack_f16(py[6], py[7]);
        *(uint4*)k1 = a;
        a.x = pack_f16(vr[0].x, vr[1].x); a.y = pack_f16(vr[2].x, vr[3].x);
        a.z = pack_f16(vr[4].x, vr[5].x); a.w = pack_f16(vr[6].x, vr[7].x);
        *(uint4*)v0 = a;
        a.x = pack_f16(vr[0].y, vr[1].y); a.y = pack_f16(vr[2].y, vr[3].y);
        a.z = pack_f16(vr[4].y, vr[5].y); a.w = pack_f16(vr[6].y, vr[7].y);
        *(uint4*)v1 = a;
    };

    auto mfma1 = [&](int buf) {
        const uint32_t* bk = lds + (buf ? OFF_K1 : OFF_K0);
        const uint32_t* bv = lds + (buf ? OFF_V1 : OFF_V0);
        const int swz = (l15 >> 1) & 7;
        #pragma unroll
        for (int ks = 0; ks < 2; ++ks) {           // K=32 tokens per MFMA step
            const int coff = (((ks * 4 + qd) ^ swz) << 2);
            FragU af;
            const uint4 ta = *(const uint4*)(bv + (wv * 16 + l15) * 32 + coff);
            af.u[0] = ta.x; af.u[1] = ta.y; af.u[2] = ta.z; af.u[3] = ta.w;
            #pragma unroll
            for (int td = 0; td < 8; ++td) {
                const uint4 tb = *(const uint4*)(bk + (td * 16 + l15) * 32 + coff);
                FragU bf;
                bf.u[0] = tb.x; bf.u[1] = tb.y; bf.u[2] = tb.z; bf.u[3] = tb.w;
                acc[td] = __builtin_amdgcn_mfma_f32_16x16x32_f16(af.v, bf.v, acc[td], 0, 0, 0);
            }
        }
    };

    loadkv(0);
    stagekv(0);          // chunk 0 -> buf0 (waits its loads)
    loadkv(1);
    __syncthreads();
    for (int ch = 0; ch < NCH; ++ch) {
        if (ch + 1 < NCH) stagekv((ch + 1) & 1);   // stage regs (chunk ch+1) -> other buf
        if (ch + 2 < NCH) loadkv(ch + 2);          // prefetch ch+2 while MFMA(ch) runs
        mfma1(ch & 1);
        __syncthreads();
    }

    atomicAdd(&ldsf[OFF_Z + 2 * dp],     z0);
    atomicAdd(&ldsf[OFF_Z + 2 * dp + 1], z1);

    // Spill S^T (fp16) to LDS: C/D layout row = wv*16 + qd*4 + r, col = td*16 + l15
    #pragma unroll
    for (int td = 0; td < 8; ++td)
        #pragma unroll
        for (int r = 0; r < 4; ++r)
            ldsh[(wv * 16 + qd * 4 + r) * (ST_STRIDE * 2) + td * 16 + l15] = (_Float16)acc[td][r];

    __syncthreads();     // sT + Z + phi-param copies all visible

    // ---------------- Phase 2: num = phi_Q * S, den = phi_Q . Z ----------------
    // Barrier-free: each wave independently streams its 64 q-rows. A-fragments of
    // phi_Q are built in registers directly from global loads (lane = row l15,
    // k-dims = ks*32 + qd*8 + j), den reduced via shfl_xor across the 4 qd groups.
    // tn-outer MFMA loop: one f32x4 accumulator per output tile (reg diet).
    const float* qb = qg + base;
    float* ob = outg + base;

    #pragma unroll 1
    for (int mt = 0; mt < 4; ++mt) {
        const int rowA = wv * 64 + mt * 16 + l15;
        const float* qrow = qb + (size_t)rowA * DDIM;

        FragU af[4];
        float den = 0.0f;
        #pragma unroll
        for (int ks = 0; ks < 4; ++ks) {
            const int dofs = ks * 32 + qd * 8;
            const f32x4 qa  = *(const f32x4*)(qrow + dofs);
            const f32x4 qc  = *(const f32x4*)(qrow + dofs + 4);
            const f32x4 sa  = *(const f32x4*)(ldsf + OFF_SC + dofs);
            const f32x4 sb  = *(const f32x4*)(ldsf + OFF_SC + dofs + 4);
            const f32x4 ba  = *(const f32x4*)(ldsf + OFF_SB + dofs);
            const f32x4 bbv = *(const f32x4*)(ldsf + OFF_SB + dofs + 4);
            const f32x4 za  = *(const f32x4*)(ldsf + OFF_Z + dofs);
            const f32x4 zb  = *(const f32x4*)(ldsf + OFF_Z + dofs + 4);
            float p[8];
            #pragma unroll
            for (int j = 0; j < 4; ++j) {
                p[j]     = phi_fn(qa[j], sa[j], ba[j]);
                p[4 + j] = phi_fn(qc[j], sb[j], bbv[j]);
                den += p[j] * za[j] + p[4 + j] * zb[j];
            }
            af[ks].u[0] = pack_f16(p[0], p[1]);
            af[ks].u[1] = pack_f16(p[2], p[3]);
            af[ks].u[2] = pack_f16(p[4], p[5]);
            af[ks].u[3] = pack_f16(p[6], p[7]);
        }
        den += __shfl_xor(den, 16);
        den += __shfl_xor(den, 32);    // all lanes: den for row (.. + l15)

        // rden for this thread's 4 store rows (row = qd*4+r within the m-tile)
        float rden[4];
        #pragma unroll
        for (int r = 0; r < 4; ++r)
            rden[r] = 1.0f / (__shfl(den, qd * 4 + r) + 1e-6f);

        float* obm = ob + (size_t)(wv * 64 + mt * 16 + qd * 4) * DDIM;

        #pragma unroll 2
        for (int tn = 0; tn < 8; ++tn) {
            f32x4 a2 = (f32x4){0.f, 0.f, 0.f, 0.f};
            #pragma unroll
            for (int ks = 0; ks < 4; ++ks) {
                const uint4 t1 = *(const uint4*)(lds + OFF_ST + (tn * 16 + l15) * ST_STRIDE + ks * 16 + qd * 4);
                FragU bf;
                bf.u[0] = t1.x; bf.u[1] = t1.y; bf.u[2] = t1.z; bf.u[3] = t1.w;
                a2 = __builtin_amdgcn_mfma_f32_16x16x32_f16(af[ks].v, bf.v, a2, 0, 0, 0);
            }
            // Epilogue for this output tile: out = num / (den + eps)
            #pragma unroll
            for (int r = 0; r < 4; ++r)
                __builtin_nontemporal_store(a2[r] * rden[r],
                                            obm + (size_t)r * DDIM + tn * 16 + l15);
        }
    }
}

extern "C" void kernel_launch(void* const* d_in, const int* in_sizes, int n_in,
                              void* d_out, int out_size, void* d_ws, size_t ws_size,
                              hipStream_t stream) {
    const float* q  = (const float*)d_in[0];
    const float* k  = (const float*)d_in[1];
    const float* v  = (const float*)d_in[2];
    const float* ps = (const float*)d_in[3];
    const float* pb = (const float*)d_in[4];
    float* out = (float*)d_out;
    // grid = B*H*nb = 2*32*8 = 512 workgroups, 512 threads (8 waves) each
    linattn_kernel<<<dim3(512), dim3(512), 0, stream>>>(q, k, v, ps, pb, out);
}